// Round 10
// baseline (518.879 us; speedup 1.0000x reference)
//
#include <hip/hip_runtime.h>
#include <hip/hip_bf16.h>

// ---------------- constants ----------------
#define T_TOK   4096
#define HID     1024
#define INTER   4096
#define NEXP    8
#define MAXT256 40          // max total 256-row tiles: 32 + 8
#define MSLOT   10240       // MAXT256 * 256
#define TPB_TOK 16          // tokens per gating block

typedef __attribute__((ext_vector_type(8))) short s16x8;
typedef __attribute__((ext_vector_type(4))) float f32x4;

__device__ __forceinline__ void load_lds16(const void* g, void* l) {
    __builtin_amdgcn_global_load_lds(
        (const __attribute__((address_space(1))) void*)g,
        (__attribute__((address_space(3))) void*)l, 16, 0, 0);
}

// gelu(tanh approx) = v * sigmoid(2*z), z = c*(v + 0.044715 v^3)
__device__ __forceinline__ float gelu_tanh(float v) {
    float c = 0.7978845608028654f;
    float z = c * (v + 0.044715f * v * v * v);
    return v / (1.0f + __expf(-2.0f * z));
}

#define VM4()  asm volatile("s_waitcnt vmcnt(4)" ::: "memory")
#define VM0()  asm volatile("s_waitcnt vmcnt(0)" ::: "memory")
#define BAR()  __builtin_amdgcn_s_barrier()
#define SCHED() __builtin_amdgcn_sched_barrier(0)

// ---------------- transpose+convert weights: in [E][R][C] f32 -> out [E][C][R] bf16 ----------------
__global__ void transpose_bf16_kernel(const float* __restrict__ in, __hip_bfloat16* __restrict__ out,
                                      int R, int C) {
    __shared__ float tile[64][65];
    size_t eoff = (size_t)blockIdx.z * R * C;
    int c0 = blockIdx.x * 64, r0 = blockIdx.y * 64;
    int tid = threadIdx.x;

    int lr = tid >> 4;            // 0..15
    int lc = (tid & 15) * 4;
    #pragma unroll
    for (int it = 0; it < 4; ++it) {
        int r = it * 16 + lr;
        float4 v = *(const float4*)(in + eoff + (size_t)(r0 + r) * C + c0 + lc);
        tile[r][lc + 0] = v.x; tile[r][lc + 1] = v.y;
        tile[r][lc + 2] = v.z; tile[r][lc + 3] = v.w;
    }
    __syncthreads();

    int oc = tid >> 3;            // 0..31
    int r8 = (tid & 7) * 8;
    #pragma unroll
    for (int it = 0; it < 2; ++it) {
        int c = it * 32 + oc;
        alignas(16) __hip_bfloat16 o[8];
        #pragma unroll
        for (int j = 0; j < 8; ++j) o[j] = __float2bfloat16(tile[r8 + j][c]);
        *(s16x8*)(out + eoff + (size_t)(c0 + c) * R + r0 + r8) = *(const s16x8*)o;
    }
}

// ---------------- gating: 16 tokens per block, block-aggregated atomics ----------------
__global__ void gating_kernel(const float* __restrict__ x, const float* __restrict__ Wg,
                              __hip_bfloat16* __restrict__ xb,
                              float* __restrict__ combine, int* __restrict__ counts,
                              float* __restrict__ prob_sums, int* __restrict__ idxcap) {
    __shared__ float s_ps[NEXP];
    __shared__ int   s_cnt[NEXP];
    __shared__ int   s_base[NEXP];
    __shared__ int   s_ei[TPB_TOK][2];
    __shared__ int   s_rk[TPB_TOK][2];

    int tid = threadIdx.x, wv = tid >> 6, ln = tid & 63;
    if (tid < NEXP) { s_ps[tid] = 0.f; s_cnt[tid] = 0; }
    __syncthreads();

    int t0 = blockIdx.x * TPB_TOK;
    for (int sub = 0; sub < 4; ++sub) {
        int tl = wv * 4 + sub;          // 0..15 local token
        int t = t0 + tl;
        const float* xr = x + (size_t)t * HID + ln * 16;
        float4 xv[4];
        #pragma unroll
        for (int i = 0; i < 4; ++i) xv[i] = *(const float4*)(xr + i * 4);

        alignas(16) __hip_bfloat16 row[16];
        #pragma unroll
        for (int i = 0; i < 4; ++i) {
            row[i * 4 + 0] = __float2bfloat16(xv[i].x);
            row[i * 4 + 1] = __float2bfloat16(xv[i].y);
            row[i * 4 + 2] = __float2bfloat16(xv[i].z);
            row[i * 4 + 3] = __float2bfloat16(xv[i].w);
        }
        __hip_bfloat16* xbr = xb + (size_t)t * HID + ln * 16;
        *(s16x8*)(xbr)     = *(s16x8*)&row[0];
        *(s16x8*)(xbr + 8) = *(s16x8*)&row[8];

        float acc[NEXP] = {0,0,0,0,0,0,0,0};
        #pragma unroll
        for (int i = 0; i < 4; ++i) {
            float xs[4] = {xv[i].x, xv[i].y, xv[i].z, xv[i].w};
            #pragma unroll
            for (int j = 0; j < 4; ++j) {
                int k = ln * 16 + i * 4 + j;
                float4 wa = *(const float4*)(Wg + (size_t)k * 8);
                float4 wb = *(const float4*)(Wg + (size_t)k * 8 + 4);
                acc[0] += xs[j] * wa.x; acc[1] += xs[j] * wa.y;
                acc[2] += xs[j] * wa.z; acc[3] += xs[j] * wa.w;
                acc[4] += xs[j] * wb.x; acc[5] += xs[j] * wb.y;
                acc[6] += xs[j] * wb.z; acc[7] += xs[j] * wb.w;
            }
        }
        #pragma unroll
        for (int e = 0; e < NEXP; ++e)
            #pragma unroll
            for (int off = 32; off >= 1; off >>= 1)
                acc[e] += __shfl_xor(acc[e], off);

        float m = acc[0];
        #pragma unroll
        for (int e = 1; e < NEXP; ++e) m = fmaxf(m, acc[e]);
        float p[NEXP], s = 0.f;
        #pragma unroll
        for (int e = 0; e < NEXP; ++e) { p[e] = __expf(acc[e] - m); s += p[e]; }
        float inv = 1.0f / s;
        #pragma unroll
        for (int e = 0; e < NEXP; ++e) p[e] *= inv;

        int i0 = 0;
        #pragma unroll
        for (int e = 1; e < NEXP; ++e) if (p[e] > p[i0]) i0 = e;
        int i1 = (i0 == 0) ? 1 : 0;
        #pragma unroll
        for (int e = 0; e < NEXP; ++e) if (e != i0 && p[e] > p[i1]) i1 = e;
        float gs = p[i0] + p[i1];
        float g0 = p[i0] / gs, g1 = p[i1] / gs;

        if (ln == 0) {
            float rowc[NEXP] = {0,0,0,0,0,0,0,0};
            rowc[i0] = g0; rowc[i1] = g1;
            float4* cr = (float4*)(combine + (size_t)t * NEXP);
            cr[0] = make_float4(rowc[0], rowc[1], rowc[2], rowc[3]);
            cr[1] = make_float4(rowc[4], rowc[5], rowc[6], rowc[7]);
            #pragma unroll
            for (int e = 0; e < NEXP; ++e) atomicAdd(&s_ps[e], p[e]);
            int r0 = atomicAdd(&s_cnt[i0], 1);
            int r1 = atomicAdd(&s_cnt[i1], 1);
            s_ei[tl][0] = i0; s_rk[tl][0] = r0;
            s_ei[tl][1] = i1; s_rk[tl][1] = r1;
        }
    }
    __syncthreads();
    if (tid < NEXP) {
        s_base[tid] = atomicAdd(&counts[tid], s_cnt[tid]);
        atomicAdd(&prob_sums[tid], s_ps[tid]);
    }
    __syncthreads();
    if (tid < TPB_TOK * 2) {
        int tl = tid >> 1, k = tid & 1;
        int e = s_ei[tl][k];
        idxcap[e * T_TOK + s_base[e] + s_rk[tl][k]] = t0 + tl;
    }
}

// ---------------- plan: offsets, 256-row tile table, aux loss (1 thread) ----------------
__global__ void plan_kernel(const int* __restrict__ counts, const float* __restrict__ prob_sums,
                            int* __restrict__ offs, int* __restrict__ tile_e,
                            int* __restrict__ tile_s0, int* __restrict__ tile_nv,
                            int* __restrict__ ntiles, float* __restrict__ aux_out) {
    int tt = 0, o = 0;
    for (int e = 0; e < NEXP; ++e) {
        offs[e] = o;
        int n = counts[e];
        int nt = (n + 255) >> 8;
        for (int r = 0; r < nt; ++r) {
            tile_e[tt] = e;
            tile_s0[tt] = o + r * 256;
            int nv = n - r * 256; if (nv > 256) nv = 256;
            tile_nv[tt] = nv;
            ++tt;
        }
        o += nt * 256;
    }
    *ntiles = tt;
    float aux = 0.f;
    for (int e = 0; e < NEXP; ++e)
        aux += ((float)counts[e] / (float)(T_TOK * 2)) * (prob_sums[e] / (float)T_TOK);
    aux_out[0] = (float)NEXP * aux * 0.01f;
}

// ---------------- compact token list ----------------
__global__ void compact_kernel(const int* __restrict__ counts, const int* __restrict__ offs,
                               const int* __restrict__ tile_e, const int* __restrict__ tile_s0,
                               const int* __restrict__ ntiles,
                               const int* __restrict__ idxcap, int* __restrict__ idxc) {
    int tt = blockIdx.x;
    if (tt >= *ntiles) return;
    int e = tile_e[tt];
    int slot = tile_s0[tt] + threadIdx.x;
    int i = slot - offs[e];
    int n = counts[e];
    idxc[slot] = (i < n) ? idxcap[e * T_TOK + i] : 0;
}

// ============ 256x256 / 8-wave / 8-phase GEMM (m201-style) ============
// LDS: As/Bs[2 dbuf][2 K-half][256][32] bf16 = 128 KB. 1 block/CU by design.
// Per K-tile (64 K = 2 half-slots of 32): 4 phases, each
//   { 8 ds_read_b128 (quadrant ks x mh) | stage ONE half (2 gload_lds) |
//     barrier | setprio(1) 16 MFMA setprio(0) | [vmcnt(4) at half boundary] | barrier }
// Stage order ph1..ph4: A(t+1,k0) B(t+1,k0) A(t+1,k1) B(t+1,k1) -> per-wave FIFO
// guarantees vmcnt(4) drains exactly the next-needed half-slots; 4 loads stay in flight.
// Swizzle (measured 0-conflict in R7): src slot (ln&3)^((ln>>3)&3), read (ln>>4)^((lr>>1)&3).

#define PH_READ(AS, BS, P, KS, MH) \
    _Pragma("unroll") for (int mm = 0; mm < 4; ++mm) { \
        int row_ = wr * 128 + ((MH) * 4 + mm) * 16 + lr; \
        af[mm] = *(const s16x8*)((const char*)&AS[P][KS][0][0] + row_ * 64 + pA); } \
    _Pragma("unroll") for (int nn = 0; nn < 4; ++nn) { \
        int row_ = wc * 64 + nn * 16 + lr; \
        bf[nn] = *(const s16x8*)((const char*)&BS[P][KS][0][0] + row_ * 64 + pA); }

#define PH_MFMA(MH) \
    __builtin_amdgcn_s_setprio(1); \
    _Pragma("unroll") for (int mm = 0; mm < 4; ++mm) \
        _Pragma("unroll") for (int nn = 0; nn < 4; ++nn) \
            acc[(MH) * 4 + mm][nn] = __builtin_amdgcn_mfma_f32_16x16x32_bf16( \
                af[mm], bf[nn], acc[(MH) * 4 + mm][nn], 0, 0, 0); \
    __builtin_amdgcn_s_setprio(0);

// ---------------- GEMM1: h[slot] = gelu(x[tok] @ w1[e] + b1[e]) ----------------
__global__ __launch_bounds__(512, 2)
void gemm1_kernel(const __hip_bfloat16* __restrict__ xb,    // [T][H]
                  const __hip_bfloat16* __restrict__ w1b,   // [E][INTER][H]  (K-major)
                  const float* __restrict__ b1,             // [E][INTER]
                  const int* __restrict__ idxc,
                  const int* __restrict__ tile_e, const int* __restrict__ tile_s0,
                  const int* __restrict__ ntiles,
                  __hip_bfloat16* __restrict__ h)           // [MSLOT][INTER]
{
    const int NWG = MAXT256 * (INTER / 256);                // 640, %8==0
    int bid = blockIdx.x;
    int w = (bid & 7) * (NWG / 8) + (bid >> 3);             // XCD-chunked
    int tt = w >> 4;                                        // n0-fast
    int n0 = (w & 15) * 256;
    if (tt >= *ntiles) return;
    int e = tile_e[tt];
    int slot0 = tile_s0[tt];

    __shared__ __hip_bfloat16 As[2][2][256][32];
    __shared__ __hip_bfloat16 Bs[2][2][256][32];
    __shared__ int s_idx[256];

    int tid = threadIdx.x, wid = tid >> 6, ln = tid & 63;
    if (tid < 256) s_idx[tid] = idxc[slot0 + tid];
    __syncthreads();

    int sg = ((ln & 3) ^ ((ln >> 3) & 3)) * 8;              // source k-chunk (elems)
    int rA0 = wid * 32 + (ln >> 2);
    unsigned offA[2], offB[2];
    #pragma unroll
    for (int j = 0; j < 2; ++j) {
        offA[j] = (unsigned)(s_idx[rA0 + j * 16] * HID) + sg;
        offB[j] = (unsigned)((e * INTER + n0 + rA0 + j * 16) * HID) + sg;
    }

    f32x4 acc[8][4] = {};
    int wr = wid >> 2, wc = wid & 3, lr = ln & 15;
    int pA = ((ln >> 4) ^ ((lr >> 1) & 3)) * 16;            // read phys slot (bytes)

    #define G1_STA(B, HF, KB) \
        load_lds16(xb + offA[0] + (KB), (void*)&As[B][HF][wid * 32][0]); \
        load_lds16(xb + offA[1] + (KB), (void*)&As[B][HF][wid * 32 + 16][0]);
    #define G1_STB(B, HF, KB) \
        load_lds16(w1b + offB[0] + (KB), (void*)&Bs[B][HF][wid * 32][0]); \
        load_lds16(w1b + offB[1] + (KB), (void*)&Bs[B][HF][wid * 32 + 16][0]);

    // prologue: stage tile 0 (both halves), FIFO: [A00 A00 B00 B00 A01 A01 B01 B01]
    G1_STA(0, 0, 0); G1_STB(0, 0, 0); G1_STA(0, 1, 32); G1_STB(0, 1, 32);
    VM4(); BAR(); SCHED();

    const int NKT = HID / 64;                               // 16
    for (int t = 0; t < NKT - 1; ++t) {
        int p = t & 1, np = p ^ 1;
        int kb = (t + 1) * 64;
        { s16x8 af[4], bf[4]; PH_READ(As, Bs, p, 0, 0) G1_STA(np, 0, kb)
          BAR(); PH_MFMA(0) BAR(); }
        { s16x8 af[4], bf[4]; PH_READ(As, Bs, p, 0, 1) G1_STB(np, 0, kb)
          BAR(); PH_MFMA(1) VM4(); BAR(); SCHED(); }
        { s16x8 af[4], bf[4]; PH_READ(As, Bs, p, 1, 0) G1_STA(np, 1, kb + 32)
          BAR(); PH_MFMA(0) BAR(); }
        { s16x8 af[4], bf[4]; PH_READ(As, Bs, p, 1, 1) G1_STB(np, 1, kb + 32)
          BAR(); PH_MFMA(1) VM4(); BAR(); SCHED(); }
    }
    {   // peeled last tile: no stages; mid-boundary drains fully
        int p = (NKT - 1) & 1;
        { s16x8 af[4], bf[4]; PH_READ(As, Bs, p, 0, 0) BAR(); PH_MFMA(0) BAR(); }
        { s16x8 af[4], bf[4]; PH_READ(As, Bs, p, 0, 1) BAR(); PH_MFMA(1) VM0(); BAR(); SCHED(); }
        { s16x8 af[4], bf[4]; PH_READ(As, Bs, p, 1, 0) BAR(); PH_MFMA(0) BAR(); }
        { s16x8 af[4], bf[4]; PH_READ(As, Bs, p, 1, 1) BAR(); PH_MFMA(1) BAR(); }
    }
    #undef G1_STA
    #undef G1_STB

    const float* b1e = b1 + (size_t)e * INTER;
    int rq = (ln >> 4) * 4;
    #pragma unroll
    for (int m = 0; m < 8; ++m) {
        #pragma unroll
        for (int r = 0; r < 4; ++r) {
            int row = wr * 128 + m * 16 + rq + r;
            size_t hrow = (size_t)(slot0 + row) * INTER;
            #pragma unroll
            for (int n = 0; n < 4; ++n) {
                int col = n0 + wc * 64 + n * 16 + lr;
                float v = acc[m][n][r] + b1e[col];
                h[hrow + col] = __float2bfloat16(gelu_tanh(v));
            }
        }
    }
}

// ---------------- GEMM2 (split-K=2): out[tok] += g * (h[slot] @ w2[e] + b2[e]) ----------------
__global__ __launch_bounds__(512, 2)
void gemm2_kernel(const __hip_bfloat16* __restrict__ h,     // [MSLOT][INTER]
                  const __hip_bfloat16* __restrict__ w2b,   // [E][H][INTER]  (K-major)
                  const float* __restrict__ b2,             // [E][H]
                  const float* __restrict__ combine,        // [T][E]
                  const int* __restrict__ idxc,
                  const int* __restrict__ tile_e, const int* __restrict__ tile_s0,
                  const int* __restrict__ tile_nv, const int* __restrict__ ntiles,
                  float* __restrict__ out)                  // [T][H]
{
    const int NWG = MAXT256 * (HID / 256) * 2;              // 320, %8==0
    int bid = blockIdx.x;
    int w = (bid & 7) * (NWG / 8) + (bid >> 3);             // XCD-chunked
    int ks = w & 1;
    int n0 = ((w >> 1) & 3) * 256;
    int tt = w >> 3;
    if (tt >= *ntiles) return;
    int e = tile_e[tt];
    int slot0 = tile_s0[tt];

    __shared__ __hip_bfloat16 As[2][2][256][32];
    __shared__ __hip_bfloat16 Bs[2][2][256][32];
    __shared__ int s_idx[256];

    int tid = threadIdx.x, wid = tid >> 6, ln = tid & 63;
    if (tid < 256) s_idx[tid] = idxc[slot0 + tid];
    __syncthreads();

    int sg = ((ln & 3) ^ ((ln >> 3) & 3)) * 8;
    int rA0 = wid * 32 + (ln >> 2);
    unsigned offA[2], offB[2];
    #pragma unroll
    for (int j = 0; j < 2; ++j) {
        offA[j] = (unsigned)((slot0 + rA0 + j * 16) * INTER) + sg;
        offB[j] = (unsigned)((e * HID + n0 + rA0 + j * 16) * INTER) + sg;
    }

    f32x4 acc[8][4] = {};
    int wr = wid >> 2, wc = wid & 3, lr = ln & 15;
    int pA = ((ln >> 4) ^ ((lr >> 1) & 3)) * 16;

    #define G2_STA(B, HF, KB) \
        load_lds16(h + offA[0] + (KB), (void*)&As[B][HF][wid * 32][0]); \
        load_lds16(h + offA[1] + (KB), (void*)&As[B][HF][wid * 32 + 16][0]);
    #define G2_STB(B, HF, KB) \
        load_lds16(w2b + offB[0] + (KB), (void*)&Bs[B][HF][wid * 32][0]); \
        load_lds16(w2b + offB[1] + (KB), (void*)&Bs[B][HF][wid * 32 + 16][0]);

    int k0 = ks * (INTER / 2);
    G2_STA(0, 0, k0); G2_STB(0, 0, k0); G2_STA(0, 1, k0 + 32); G2_STB(0, 1, k0 + 32);
    VM4(); BAR(); SCHED();

    const int NKT = (INTER / 2) / 64;                       // 32
    for (int t = 0; t < NKT - 1; ++t) {
        int p = t & 1, np = p ^ 1;
        int kb = k0 + (t + 1) * 64;
        { s16x8 af[4], bf[4]; PH_READ(As, Bs, p, 0, 0) G2_STA(np, 0, kb)
          BAR(); PH_MFMA(0) BAR(); }
        { s16x8 af[4], bf[4]; PH_READ(As, Bs, p, 0, 1) G2_STB(np, 0, kb)
          BAR(); PH_MFMA(1) VM4(); BAR(); SCHED(); }
        { s16x8 af[4], bf[4]; PH_READ(As, Bs, p, 1, 0) G2_STA(np, 1, kb + 32)
          BAR(); PH_MFMA(0) BAR(); }
        { s16x8 af[4], bf[4]; PH_READ(As, Bs, p, 1, 1) G2_STB(np, 1, kb + 32)
          BAR(); PH_MFMA(1) VM4(); BAR(); SCHED(); }
    }
    {
        int p = (NKT - 1) & 1;
        { s16x8 af[4], bf[4]; PH_READ(As, Bs, p, 0, 0) BAR(); PH_MFMA(0) BAR(); }
        { s16x8 af[4], bf[4]; PH_READ(As, Bs, p, 0, 1) BAR(); PH_MFMA(1) VM0(); BAR(); SCHED(); }
        { s16x8 af[4], bf[4]; PH_READ(As, Bs, p, 1, 0) BAR(); PH_MFMA(0) BAR(); }
        { s16x8 af[4], bf[4]; PH_READ(As, Bs, p, 1, 1) BAR(); PH_MFMA(1) BAR(); }
    }
    #undef G2_STA
    #undef G2_STB

    const float* b2e = b2 + (size_t)e * HID;
    int nv = tile_nv[tt];
    int rq = (ln >> 4) * 4;
    #pragma unroll
    for (int m = 0; m < 8; ++m) {
        #pragma unroll
        for (int r = 0; r < 4; ++r) {
            int row = wr * 128 + m * 16 + rq + r;
            if (row < nv) {
                int tok = s_idx[row];
                float g = combine[(size_t)tok * 8 + e];
                #pragma unroll
                for (int n = 0; n < 4; ++n) {
                    int col = n0 + wc * 64 + n * 16 + lr;
                    float v = acc[m][n][r] + (ks == 0 ? b2e[col] : 0.f);
                    atomicAdd(&out[(size_t)tok * HID + col], g * v);
                }
            }
        }
    }
}

// ---------------- workspace layout ----------------
static const size_t OFF_XB      = 0;
static const size_t SZ_XB       = (size_t)T_TOK * HID * 2;
static const size_t OFF_W1B     = OFF_XB + SZ_XB;
static const size_t SZ_W        = (size_t)NEXP * INTER * HID * 2;
static const size_t OFF_W2B     = OFF_W1B + SZ_W;
static const size_t OFF_H       = OFF_W2B + SZ_W;
static const size_t SZ_H        = (size_t)MSLOT * INTER * 2;
static const size_t OFF_COMBINE = OFF_H + SZ_H;
static const size_t OFF_IDXCAP  = OFF_COMBINE + (size_t)T_TOK * 8 * 4;
static const size_t OFF_IDXC    = OFF_IDXCAP + (size_t)NEXP * T_TOK * 4;
static const size_t OFF_COUNTS  = OFF_IDXC + (size_t)MSLOT * 4;     // 8 ints
static const size_t OFF_PSUMS   = OFF_COUNTS + 32;                  // 8 floats
static const size_t OFF_OFFS    = OFF_PSUMS + 32;                   // 8 ints
static const size_t OFF_TILE_E  = OFF_OFFS + 64;
static const size_t OFF_TILE_S0 = OFF_TILE_E + 512;
static const size_t OFF_TILE_NV = OFF_TILE_S0 + 512;
static const size_t OFF_NTILES  = OFF_TILE_NV + 512;

extern "C" void kernel_launch(void* const* d_in, const int* in_sizes, int n_in,
                              void* d_out, int out_size, void* d_ws, size_t ws_size,
                              hipStream_t stream) {
    const float* x  = (const float*)d_in[0];
    const float* Wg = (const float*)d_in[1];
    const float* w1 = (const float*)d_in[2];
    const float* b1 = (const float*)d_in[3];
    const float* w2 = (const float*)d_in[4];
    const float* b2 = (const float*)d_in[5];
    float* out = (float*)d_out;
    char* ws = (char*)d_ws;

    __hip_bfloat16* xb   = (__hip_bfloat16*)(ws + OFF_XB);
    __hip_bfloat16* w1b  = (__hip_bfloat16*)(ws + OFF_W1B);
    __hip_bfloat16* w2b  = (__hip_bfloat16*)(ws + OFF_W2B);
    __hip_bfloat16* h    = (__hip_bfloat16*)(ws + OFF_H);
    float* combine       = (float*)(ws + OFF_COMBINE);
    int*   idxcap        = (int*)(ws + OFF_IDXCAP);
    int*   idxc          = (int*)(ws + OFF_IDXC);
    int*   counts        = (int*)(ws + OFF_COUNTS);
    float* psums         = (float*)(ws + OFF_PSUMS);
    int*   offs          = (int*)(ws + OFF_OFFS);
    int*   tile_e        = (int*)(ws + OFF_TILE_E);
    int*   tile_s0       = (int*)(ws + OFF_TILE_S0);
    int*   tile_nv       = (int*)(ws + OFF_TILE_NV);
    int*   ntiles        = (int*)(ws + OFF_NTILES);

    (void)hipMemsetAsync(out, 0, (size_t)out_size * sizeof(float), stream);
    (void)hipMemsetAsync(ws + OFF_COUNTS, 0, 64, stream);

    transpose_bf16_kernel<<<dim3(INTER / 64, HID / 64, NEXP), 256, 0, stream>>>(w1, w1b, HID, INTER);
    transpose_bf16_kernel<<<dim3(HID / 64, INTER / 64, NEXP), 256, 0, stream>>>(w2, w2b, INTER, HID);
    gating_kernel<<<T_TOK / TPB_TOK, 256, 0, stream>>>(x, Wg, xb, combine, counts, psums, idxcap);
    plan_kernel<<<1, 1, 0, stream>>>(counts, psums, offs, tile_e, tile_s0, tile_nv, ntiles,
                                     out + (size_t)T_TOK * HID);
    compact_kernel<<<MAXT256, 256, 0, stream>>>(counts, offs, tile_e, tile_s0, ntiles, idxcap, idxc);
    gemm1_kernel<<<MAXT256 * (INTER / 256), 512, 0, stream>>>(xb, w1b, b1, idxc, tile_e, tile_s0,
                                                              ntiles, h);
    gemm2_kernel<<<MAXT256 * (HID / 256) * 2, 512, 0, stream>>>(h, w2b, b2, combine, idxc, tile_e,
                                                                tile_s0, tile_nv, ntiles, out);
}

// Round 11
// 403.820 us; speedup vs baseline: 1.2849x; 1.2849x over previous
//
#include <hip/hip_runtime.h>
#include <hip/hip_bf16.h>

// ---------------- constants ----------------
#define T_TOK   4096
#define HID     1024
#define INTER   4096
#define NEXP    8
#define MAXT    72          // max total row-tiles: (8192 + 8*127)/128 = 72
#define MAXSLOT 9216        // MAXT * 128
#define TPB_TOK 16          // tokens per gating block

typedef __attribute__((ext_vector_type(8))) short s16x8;
typedef __attribute__((ext_vector_type(4))) float f32x4;

__device__ __forceinline__ void load_lds16(const void* g, void* l) {
    __builtin_amdgcn_global_load_lds(
        (const __attribute__((address_space(1))) void*)g,
        (__attribute__((address_space(3))) void*)l, 16, 0, 0);
}

// gelu(tanh approx) = v * sigmoid(2*z), z = c*(v + 0.044715 v^3)
__device__ __forceinline__ float gelu_tanh(float v) {
    float c = 0.7978845608028654f;
    float z = c * (v + 0.044715f * v * v * v);
    return v / (1.0f + __expf(-2.0f * z));
}

// ---------------- transpose+convert weights: in [E][R][C] f32 -> out [E][C][R] bf16 ----------------
// 64x64 tiles, float4 loads, short8 stores
__global__ void transpose_bf16_kernel(const float* __restrict__ in, __hip_bfloat16* __restrict__ out,
                                      int R, int C) {
    __shared__ float tile[64][65];
    size_t eoff = (size_t)blockIdx.z * R * C;
    int c0 = blockIdx.x * 64, r0 = blockIdx.y * 64;
    int tid = threadIdx.x;

    int lr = tid >> 4;            // 0..15
    int lc = (tid & 15) * 4;
    #pragma unroll
    for (int it = 0; it < 4; ++it) {
        int r = it * 16 + lr;
        float4 v = *(const float4*)(in + eoff + (size_t)(r0 + r) * C + c0 + lc);
        tile[r][lc + 0] = v.x; tile[r][lc + 1] = v.y;
        tile[r][lc + 2] = v.z; tile[r][lc + 3] = v.w;
    }
    __syncthreads();

    int oc = tid >> 3;            // 0..31
    int r8 = (tid & 7) * 8;
    #pragma unroll
    for (int it = 0; it < 2; ++it) {
        int c = it * 32 + oc;
        alignas(16) __hip_bfloat16 o[8];
        #pragma unroll
        for (int j = 0; j < 8; ++j) o[j] = __float2bfloat16(tile[r8 + j][c]);
        *(s16x8*)(out + eoff + (size_t)(c0 + c) * R + r0 + r8) = *(const s16x8*)o;
    }
}

// ---------------- gating: 16 tokens per block, block-aggregated atomics ----------------
__global__ void gating_kernel(const float* __restrict__ x, const float* __restrict__ Wg,
                              __hip_bfloat16* __restrict__ xb,
                              float* __restrict__ combine, int* __restrict__ counts,
                              float* __restrict__ prob_sums, int* __restrict__ idxcap) {
    __shared__ float s_ps[NEXP];
    __shared__ int   s_cnt[NEXP];
    __shared__ int   s_base[NEXP];
    __shared__ int   s_ei[TPB_TOK][2];
    __shared__ int   s_rk[TPB_TOK][2];

    int tid = threadIdx.x, wv = tid >> 6, ln = tid & 63;
    if (tid < NEXP) { s_ps[tid] = 0.f; s_cnt[tid] = 0; }
    __syncthreads();

    int t0 = blockIdx.x * TPB_TOK;
    for (int sub = 0; sub < 4; ++sub) {
        int tl = wv * 4 + sub;          // 0..15 local token
        int t = t0 + tl;
        const float* xr = x + (size_t)t * HID + ln * 16;
        float4 xv[4];
        #pragma unroll
        for (int i = 0; i < 4; ++i) xv[i] = *(const float4*)(xr + i * 4);

        alignas(16) __hip_bfloat16 row[16];
        #pragma unroll
        for (int i = 0; i < 4; ++i) {
            row[i * 4 + 0] = __float2bfloat16(xv[i].x);
            row[i * 4 + 1] = __float2bfloat16(xv[i].y);
            row[i * 4 + 2] = __float2bfloat16(xv[i].z);
            row[i * 4 + 3] = __float2bfloat16(xv[i].w);
        }
        __hip_bfloat16* xbr = xb + (size_t)t * HID + ln * 16;
        *(s16x8*)(xbr)     = *(s16x8*)&row[0];
        *(s16x8*)(xbr + 8) = *(s16x8*)&row[8];

        float acc[NEXP] = {0,0,0,0,0,0,0,0};
        #pragma unroll
        for (int i = 0; i < 4; ++i) {
            float xs[4] = {xv[i].x, xv[i].y, xv[i].z, xv[i].w};
            #pragma unroll
            for (int j = 0; j < 4; ++j) {
                int k = ln * 16 + i * 4 + j;
                float4 wa = *(const float4*)(Wg + (size_t)k * 8);
                float4 wb = *(const float4*)(Wg + (size_t)k * 8 + 4);
                acc[0] += xs[j] * wa.x; acc[1] += xs[j] * wa.y;
                acc[2] += xs[j] * wa.z; acc[3] += xs[j] * wa.w;
                acc[4] += xs[j] * wb.x; acc[5] += xs[j] * wb.y;
                acc[6] += xs[j] * wb.z; acc[7] += xs[j] * wb.w;
            }
        }
        #pragma unroll
        for (int e = 0; e < NEXP; ++e)
            #pragma unroll
            for (int off = 32; off >= 1; off >>= 1)
                acc[e] += __shfl_xor(acc[e], off);

        float m = acc[0];
        #pragma unroll
        for (int e = 1; e < NEXP; ++e) m = fmaxf(m, acc[e]);
        float p[NEXP], s = 0.f;
        #pragma unroll
        for (int e = 0; e < NEXP; ++e) { p[e] = __expf(acc[e] - m); s += p[e]; }
        float inv = 1.0f / s;
        #pragma unroll
        for (int e = 0; e < NEXP; ++e) p[e] *= inv;

        int i0 = 0;
        #pragma unroll
        for (int e = 1; e < NEXP; ++e) if (p[e] > p[i0]) i0 = e;
        int i1 = (i0 == 0) ? 1 : 0;
        #pragma unroll
        for (int e = 0; e < NEXP; ++e) if (e != i0 && p[e] > p[i1]) i1 = e;
        float gs = p[i0] + p[i1];
        float g0 = p[i0] / gs, g1 = p[i1] / gs;

        if (ln == 0) {
            float rowc[NEXP] = {0,0,0,0,0,0,0,0};
            rowc[i0] = g0; rowc[i1] = g1;
            float4* cr = (float4*)(combine + (size_t)t * NEXP);
            cr[0] = make_float4(rowc[0], rowc[1], rowc[2], rowc[3]);
            cr[1] = make_float4(rowc[4], rowc[5], rowc[6], rowc[7]);
            #pragma unroll
            for (int e = 0; e < NEXP; ++e) atomicAdd(&s_ps[e], p[e]);
            int r0 = atomicAdd(&s_cnt[i0], 1);
            int r1 = atomicAdd(&s_cnt[i1], 1);
            s_ei[tl][0] = i0; s_rk[tl][0] = r0;
            s_ei[tl][1] = i1; s_rk[tl][1] = r1;
        }
    }
    __syncthreads();
    if (tid < NEXP) {
        s_base[tid] = atomicAdd(&counts[tid], s_cnt[tid]);
        atomicAdd(&prob_sums[tid], s_ps[tid]);
    }
    __syncthreads();
    if (tid < TPB_TOK * 2) {
        int tl = tid >> 1, k = tid & 1;
        int e = s_ei[tl][k];
        idxcap[e * T_TOK + s_base[e] + s_rk[tl][k]] = t0 + tl;
    }
}

// ---------------- plan: offsets, tile table, aux loss (1 thread) ----------------
__global__ void plan_kernel(const int* __restrict__ counts, const float* __restrict__ prob_sums,
                            int* __restrict__ offs, int* __restrict__ tile_e,
                            int* __restrict__ tile_s0, int* __restrict__ tile_nv,
                            int* __restrict__ ntiles, float* __restrict__ aux_out) {
    int tt = 0, o = 0;
    for (int e = 0; e < NEXP; ++e) {
        offs[e] = o;
        int n = counts[e];
        int nt = (n + 127) >> 7;
        for (int r = 0; r < nt; ++r) {
            tile_e[tt] = e;
            tile_s0[tt] = o + r * 128;
            int nv = n - r * 128; if (nv > 128) nv = 128;
            tile_nv[tt] = nv;
            ++tt;
        }
        o += nt * 128;
    }
    *ntiles = tt;
    float aux = 0.f;
    for (int e = 0; e < NEXP; ++e)
        aux += ((float)counts[e] / (float)(T_TOK * 2)) * (prob_sums[e] / (float)T_TOK);
    aux_out[0] = (float)NEXP * aux * 0.01f;
}

// ---------------- compact token list ----------------
__global__ void compact_kernel(const int* __restrict__ counts, const int* __restrict__ offs,
                               const int* __restrict__ tile_e, const int* __restrict__ tile_s0,
                               const int* __restrict__ ntiles,
                               const int* __restrict__ idxcap, int* __restrict__ idxc) {
    int tt = blockIdx.x;
    if (tt >= *ntiles) return;
    int e = tile_e[tt];
    int slot = tile_s0[tt] + threadIdx.x;
    int i = slot - offs[e];
    int n = counts[e];
    idxc[slot] = (i < n) ? idxcap[e * T_TOK + i] : 0;
}

// ============ GEMM template (R6 best-known) ============
// LDS tile [128][64] bf16, single-buffered, two barriers/iter (m97 structure).
// XOR swizzle (measured 0-conflict): LDS slot s of row r holds global k-slot
// s^(r&7); global source pre-swizzled so global_load_lds dest stays linear.

// ---------------- GEMM1: h[slot] = gelu(x[tok] @ w1[e] + b1[e]) ----------------
__global__ __launch_bounds__(256, 3)
void gemm1_kernel(const __hip_bfloat16* __restrict__ xb,    // [T][H]
                  const __hip_bfloat16* __restrict__ w1b,   // [E][INTER][H]  (K-major)
                  const float* __restrict__ b1,             // [E][INTER]
                  const int* __restrict__ idxc,
                  const int* __restrict__ tile_e, const int* __restrict__ tile_s0,
                  const int* __restrict__ ntiles,
                  __hip_bfloat16* __restrict__ h)           // [MAXSLOT][INTER]
{
    const int NWG = MAXT * (INTER / 128);                   // 2304, %8==0
    int bid = blockIdx.x;
    int w = (bid & 7) * (NWG / 8) + (bid >> 3);             // XCD-chunked
    int tt = w >> 5;                                        // n0-fast
    int n0 = (w & 31) * 128;
    if (tt >= *ntiles) return;
    int e = tile_e[tt];
    int slot0 = tile_s0[tt];

    __shared__ __hip_bfloat16 As[128][64];
    __shared__ __hip_bfloat16 Bs[128][64];
    __shared__ int s_idx[128];

    int tid = threadIdx.x, wv = tid >> 6, ln = tid & 63;
    if (tid < 128) s_idx[tid] = idxc[slot0 + tid];
    __syncthreads();

    int swz = ((ln & 7) ^ (ln >> 3)) * 8;                   // pre-swizzled k-offset (elems)
    const __hip_bfloat16* srcA[4];
    const __hip_bfloat16* srcB[4];
    const __hip_bfloat16* wbase = w1b + (size_t)e * INTER * HID;
    #pragma unroll
    for (int j = 0; j < 4; ++j) {
        int r = wv * 32 + j * 8 + (ln >> 3);
        srcA[j] = xb + (size_t)s_idx[r] * HID + swz;
        srcB[j] = wbase + (size_t)(n0 + r) * HID + swz;
    }

    f32x4 acc[4][4] = {};
    int wr = wv >> 1, wc = wv & 1, lr = ln & 15;

    for (int kt = 0; kt < HID; kt += 64) {
        #pragma unroll
        for (int j = 0; j < 4; ++j) {
            load_lds16(srcA[j] + kt, (void*)&As[wv * 32 + j * 8][0]);
            load_lds16(srcB[j] + kt, (void*)&Bs[wv * 32 + j * 8][0]);
        }
        __syncthreads();
        #pragma unroll
        for (int kk = 0; kk < 2; ++kk) {
            int lslot = (((kk * 4) + (ln >> 4)) ^ (ln & 7)) * 16;
            s16x8 af[4], bf[4];
            #pragma unroll
            for (int m = 0; m < 4; ++m) {
                int row = wr * 64 + m * 16 + lr;
                af[m] = *(const s16x8*)((const char*)&As[0][0] + row * 128 + lslot);
            }
            #pragma unroll
            for (int n = 0; n < 4; ++n) {
                int row = wc * 64 + n * 16 + lr;
                bf[n] = *(const s16x8*)((const char*)&Bs[0][0] + row * 128 + lslot);
            }
            #pragma unroll
            for (int m = 0; m < 4; ++m)
                #pragma unroll
                for (int n = 0; n < 4; ++n)
                    acc[m][n] = __builtin_amdgcn_mfma_f32_16x16x32_bf16(af[m], bf[n], acc[m][n], 0, 0, 0);
        }
        __syncthreads();
    }

    const float* b1e = b1 + (size_t)e * INTER;
    int rq = (ln >> 4) * 4;
    #pragma unroll
    for (int m = 0; m < 4; ++m) {
        #pragma unroll
        for (int r = 0; r < 4; ++r) {
            int row = wr * 64 + m * 16 + rq + r;
            size_t hrow = (size_t)(slot0 + row) * INTER;
            #pragma unroll
            for (int n = 0; n < 4; ++n) {
                int col = n0 + wc * 64 + n * 16 + lr;
                float v = acc[m][n][r] + b1e[col];
                h[hrow + col] = __float2bfloat16(gelu_tanh(v));
            }
        }
    }
}

// ---------------- GEMM2 (split-K=4): out[tok] += g * (h[slot] @ w2[e] + b2[e]) ----------------
__global__ __launch_bounds__(256, 3)
void gemm2_kernel(const __hip_bfloat16* __restrict__ h,     // [MAXSLOT][INTER]
                  const __hip_bfloat16* __restrict__ w2b,   // [E][H][INTER]  (K-major)
                  const float* __restrict__ b2,             // [E][H]
                  const float* __restrict__ combine,        // [T][E]
                  const int* __restrict__ idxc,
                  const int* __restrict__ tile_e, const int* __restrict__ tile_s0,
                  const int* __restrict__ tile_nv, const int* __restrict__ ntiles,
                  float* __restrict__ out)                  // [T][H]
{
    const int NWG = MAXT * (HID / 128) * 4;                 // 2304, %8==0
    int bid = blockIdx.x;
    int w = (bid & 7) * (NWG / 8) + (bid >> 3);             // XCD-chunked
    int ks = w & 3;                                         // split-K quarter
    int n0 = ((w >> 2) & 7) * 128;
    int tt = w >> 5;
    if (tt >= *ntiles) return;
    int e = tile_e[tt];
    int slot0 = tile_s0[tt];

    __shared__ __hip_bfloat16 As[128][64];
    __shared__ __hip_bfloat16 Bs[128][64];
    __shared__ int s_idx[128];

    int tid = threadIdx.x, wv = tid >> 6, ln = tid & 63;
    if (tid < 128) s_idx[tid] = idxc[slot0 + tid];
    __syncthreads();

    int swz = ((ln & 7) ^ (ln >> 3)) * 8;
    const __hip_bfloat16* srcA[4];
    const __hip_bfloat16* srcB[4];
    const __hip_bfloat16* wbase = w2b + (size_t)e * HID * INTER;
    #pragma unroll
    for (int j = 0; j < 4; ++j) {
        int r = wv * 32 + j * 8 + (ln >> 3);
        srcA[j] = h + (size_t)(slot0 + r) * INTER + swz;
        srcB[j] = wbase + (size_t)(n0 + r) * INTER + swz;
    }

    f32x4 acc[4][4] = {};
    int wr = wv >> 1, wc = wv & 1, lr = ln & 15;

    int k0 = ks * (INTER / 4), k1 = k0 + INTER / 4;         // 1024 K per block
    for (int kt = k0; kt < k1; kt += 64) {
        #pragma unroll
        for (int j = 0; j < 4; ++j) {
            load_lds16(srcA[j] + kt, (void*)&As[wv * 32 + j * 8][0]);
            load_lds16(srcB[j] + kt, (void*)&Bs[wv * 32 + j * 8][0]);
        }
        __syncthreads();
        #pragma unroll
        for (int kk = 0; kk < 2; ++kk) {
            int lslot = (((kk * 4) + (ln >> 4)) ^ (ln & 7)) * 16;
            s16x8 af[4], bf[4];
            #pragma unroll
            for (int m = 0; m < 4; ++m) {
                int row = wr * 64 + m * 16 + lr;
                af[m] = *(const s16x8*)((const char*)&As[0][0] + row * 128 + lslot);
            }
            #pragma unroll
            for (int n = 0; n < 4; ++n) {
                int row = wc * 64 + n * 16 + lr;
                bf[n] = *(const s16x8*)((const char*)&Bs[0][0] + row * 128 + lslot);
            }
            #pragma unroll
            for (int m = 0; m < 4; ++m)
                #pragma unroll
                for (int n = 0; n < 4; ++n)
                    acc[m][n] = __builtin_amdgcn_mfma_f32_16x16x32_bf16(af[m], bf[n], acc[m][n], 0, 0, 0);
        }
        __syncthreads();
    }

    const float* b2e = b2 + (size_t)e * HID;
    int nv = tile_nv[tt];
    int rq = (ln >> 4) * 4;
    #pragma unroll
    for (int m = 0; m < 4; ++m) {
        #pragma unroll
        for (int r = 0; r < 4; ++r) {
            int row = wr * 64 + m * 16 + rq + r;
            if (row < nv) {
                int tok = s_idx[row];
                float g = combine[(size_t)tok * 8 + e];
                #pragma unroll
                for (int n = 0; n < 4; ++n) {
                    int col = n0 + wc * 64 + n * 16 + lr;
                    float v = acc[m][n][r] + (ks == 0 ? b2e[col] : 0.f);
                    atomicAdd(&out[(size_t)tok * HID + col], g * v);
                }
            }
        }
    }
}

// ---------------- workspace layout ----------------
static const size_t OFF_XB      = 0;
static const size_t SZ_XB       = (size_t)T_TOK * HID * 2;
static const size_t OFF_W1B     = OFF_XB + SZ_XB;
static const size_t SZ_W        = (size_t)NEXP * INTER * HID * 2;
static const size_t OFF_W2B     = OFF_W1B + SZ_W;
static const size_t OFF_H       = OFF_W2B + SZ_W;
static const size_t SZ_H        = (size_t)MAXSLOT * INTER * 2;
static const size_t OFF_COMBINE = OFF_H + SZ_H;
static const size_t OFF_IDXCAP  = OFF_COMBINE + (size_t)T_TOK * 8 * 4;
static const size_t OFF_IDXC    = OFF_IDXCAP + (size_t)NEXP * T_TOK * 4;
static const size_t OFF_COUNTS  = OFF_IDXC + (size_t)MAXSLOT * 4;   // 8 ints
static const size_t OFF_PSUMS   = OFF_COUNTS + 32;                  // 8 floats
static const size_t OFF_OFFS    = OFF_PSUMS + 32;                   // 8 ints
static const size_t OFF_TILE_E  = OFF_OFFS + 64;
static const size_t OFF_TILE_S0 = OFF_TILE_E + 512;
static const size_t OFF_TILE_NV = OFF_TILE_S0 + 512;
static const size_t OFF_NTILES  = OFF_TILE_NV + 512;

extern "C" void kernel_launch(void* const* d_in, const int* in_sizes, int n_in,
                              void* d_out, int out_size, void* d_ws, size_t ws_size,
                              hipStream_t stream) {
    const float* x  = (const float*)d_in[0];
    const float* Wg = (const float*)d_in[1];
    const float* w1 = (const float*)d_in[2];
    const float* b1 = (const float*)d_in[3];
    const float* w2 = (const float*)d_in[4];
    const float* b2 = (const float*)d_in[5];
    float* out = (float*)d_out;
    char* ws = (char*)d_ws;

    __hip_bfloat16* xb   = (__hip_bfloat16*)(ws + OFF_XB);
    __hip_bfloat16* w1b  = (__hip_bfloat16*)(ws + OFF_W1B);
    __hip_bfloat16* w2b  = (__hip_bfloat16*)(ws + OFF_W2B);
    __hip_bfloat16* h    = (__hip_bfloat16*)(ws + OFF_H);
    float* combine       = (float*)(ws + OFF_COMBINE);
    int*   idxcap        = (int*)(ws + OFF_IDXCAP);
    int*   idxc          = (int*)(ws + OFF_IDXC);
    int*   counts        = (int*)(ws + OFF_COUNTS);
    float* psums         = (float*)(ws + OFF_PSUMS);
    int*   offs          = (int*)(ws + OFF_OFFS);
    int*   tile_e        = (int*)(ws + OFF_TILE_E);
    int*   tile_s0       = (int*)(ws + OFF_TILE_S0);
    int*   tile_nv       = (int*)(ws + OFF_TILE_NV);
    int*   ntiles        = (int*)(ws + OFF_NTILES);

    (void)hipMemsetAsync(out, 0, (size_t)out_size * sizeof(float), stream);
    (void)hipMemsetAsync(ws + OFF_COUNTS, 0, 64, stream);

    transpose_bf16_kernel<<<dim3(INTER / 64, HID / 64, NEXP), 256, 0, stream>>>(w1, w1b, HID, INTER);
    transpose_bf16_kernel<<<dim3(HID / 64, INTER / 64, NEXP), 256, 0, stream>>>(w2, w2b, INTER, HID);
    gating_kernel<<<T_TOK / TPB_TOK, 256, 0, stream>>>(x, Wg, xb, combine, counts, psums, idxcap);
    plan_kernel<<<1, 1, 0, stream>>>(counts, psums, offs, tile_e, tile_s0, tile_nv, ntiles,
                                     out + (size_t)T_TOK * HID);
    compact_kernel<<<MAXT, 128, 0, stream>>>(counts, offs, tile_e, tile_s0, ntiles, idxcap, idxc);
    gemm1_kernel<<<MAXT * (INTER / 128), 256, 0, stream>>>(xb, w1b, b1, idxc, tile_e, tile_s0,
                                                           ntiles, h);
    gemm2_kernel<<<MAXT * (HID / 128) * 4, 256, 0, stream>>>(h, w2b, b2, combine, idxc, tile_e,
                                                             tile_s0, tile_nv, ntiles, out);
}

// Round 12
// 388.190 us; speedup vs baseline: 1.3367x; 1.0403x over previous
//
#include <hip/hip_runtime.h>
#include <hip/hip_bf16.h>

// ---------------- constants ----------------
#define T_TOK   4096
#define HID     1024
#define INTER   4096
#define NEXP    8
#define MAXT64  136         // max total 64-row tiles: 8192/64 + 8
#define MSLOT64 8704        // MAXT64 * 64
#define TPB_TOK 16          // tokens per gating block

typedef __attribute__((ext_vector_type(8))) short s16x8;
typedef __attribute__((ext_vector_type(4))) float f32x4;

__device__ __forceinline__ void load_lds16(const void* g, void* l) {
    __builtin_amdgcn_global_load_lds(
        (const __attribute__((address_space(1))) void*)g,
        (__attribute__((address_space(3))) void*)l, 16, 0, 0);
}

// gelu(tanh approx) = v * sigmoid(2*z), z = c*(v + 0.044715 v^3)
__device__ __forceinline__ float gelu_tanh(float v) {
    float c = 0.7978845608028654f;
    float z = c * (v + 0.044715f * v * v * v);
    return v / (1.0f + __expf(-2.0f * z));
}

// ---------------- transpose+convert weights: in [E][R][C] f32 -> out [E][C][R] bf16 ----------------
__global__ void transpose_bf16_kernel(const float* __restrict__ in, __hip_bfloat16* __restrict__ out,
                                      int R, int C) {
    __shared__ float tile[64][65];
    size_t eoff = (size_t)blockIdx.z * R * C;
    int c0 = blockIdx.x * 64, r0 = blockIdx.y * 64;
    int tid = threadIdx.x;

    int lr = tid >> 4;            // 0..15
    int lc = (tid & 15) * 4;
    #pragma unroll
    for (int it = 0; it < 4; ++it) {
        int r = it * 16 + lr;
        float4 v = *(const float4*)(in + eoff + (size_t)(r0 + r) * C + c0 + lc);
        tile[r][lc + 0] = v.x; tile[r][lc + 1] = v.y;
        tile[r][lc + 2] = v.z; tile[r][lc + 3] = v.w;
    }
    __syncthreads();

    int oc = tid >> 3;            // 0..31
    int r8 = (tid & 7) * 8;
    #pragma unroll
    for (int it = 0; it < 2; ++it) {
        int c = it * 32 + oc;
        alignas(16) __hip_bfloat16 o[8];
        #pragma unroll
        for (int j = 0; j < 8; ++j) o[j] = __float2bfloat16(tile[r8 + j][c]);
        *(s16x8*)(out + eoff + (size_t)(c0 + c) * R + r0 + r8) = *(const s16x8*)o;
    }
}

// ---------------- gating: 16 tokens per block, block-aggregated atomics ----------------
__global__ void gating_kernel(const float* __restrict__ x, const float* __restrict__ Wg,
                              __hip_bfloat16* __restrict__ xb,
                              float* __restrict__ combine, int* __restrict__ counts,
                              float* __restrict__ prob_sums, int* __restrict__ idxcap) {
    __shared__ float s_ps[NEXP];
    __shared__ int   s_cnt[NEXP];
    __shared__ int   s_base[NEXP];
    __shared__ int   s_ei[TPB_TOK][2];
    __shared__ int   s_rk[TPB_TOK][2];

    int tid = threadIdx.x, wv = tid >> 6, ln = tid & 63;
    if (tid < NEXP) { s_ps[tid] = 0.f; s_cnt[tid] = 0; }
    __syncthreads();

    int t0 = blockIdx.x * TPB_TOK;
    for (int sub = 0; sub < 4; ++sub) {
        int tl = wv * 4 + sub;          // 0..15 local token
        int t = t0 + tl;
        const float* xr = x + (size_t)t * HID + ln * 16;
        float4 xv[4];
        #pragma unroll
        for (int i = 0; i < 4; ++i) xv[i] = *(const float4*)(xr + i * 4);

        alignas(16) __hip_bfloat16 row[16];
        #pragma unroll
        for (int i = 0; i < 4; ++i) {
            row[i * 4 + 0] = __float2bfloat16(xv[i].x);
            row[i * 4 + 1] = __float2bfloat16(xv[i].y);
            row[i * 4 + 2] = __float2bfloat16(xv[i].z);
            row[i * 4 + 3] = __float2bfloat16(xv[i].w);
        }
        __hip_bfloat16* xbr = xb + (size_t)t * HID + ln * 16;
        *(s16x8*)(xbr)     = *(s16x8*)&row[0];
        *(s16x8*)(xbr + 8) = *(s16x8*)&row[8];

        float acc[NEXP] = {0,0,0,0,0,0,0,0};
        #pragma unroll
        for (int i = 0; i < 4; ++i) {
            float xs[4] = {xv[i].x, xv[i].y, xv[i].z, xv[i].w};
            #pragma unroll
            for (int j = 0; j < 4; ++j) {
                int k = ln * 16 + i * 4 + j;
                float4 wa = *(const float4*)(Wg + (size_t)k * 8);
                float4 wb = *(const float4*)(Wg + (size_t)k * 8 + 4);
                acc[0] += xs[j] * wa.x; acc[1] += xs[j] * wa.y;
                acc[2] += xs[j] * wa.z; acc[3] += xs[j] * wa.w;
                acc[4] += xs[j] * wb.x; acc[5] += xs[j] * wb.y;
                acc[6] += xs[j] * wb.z; acc[7] += xs[j] * wb.w;
            }
        }
        #pragma unroll
        for (int e = 0; e < NEXP; ++e)
            #pragma unroll
            for (int off = 32; off >= 1; off >>= 1)
                acc[e] += __shfl_xor(acc[e], off);

        float m = acc[0];
        #pragma unroll
        for (int e = 1; e < NEXP; ++e) m = fmaxf(m, acc[e]);
        float p[NEXP], s = 0.f;
        #pragma unroll
        for (int e = 0; e < NEXP; ++e) { p[e] = __expf(acc[e] - m); s += p[e]; }
        float inv = 1.0f / s;
        #pragma unroll
        for (int e = 0; e < NEXP; ++e) p[e] *= inv;

        int i0 = 0;
        #pragma unroll
        for (int e = 1; e < NEXP; ++e) if (p[e] > p[i0]) i0 = e;
        int i1 = (i0 == 0) ? 1 : 0;
        #pragma unroll
        for (int e = 0; e < NEXP; ++e) if (e != i0 && p[e] > p[i1]) i1 = e;
        float gs = p[i0] + p[i1];
        float g0 = p[i0] / gs, g1 = p[i1] / gs;

        if (ln == 0) {
            float rowc[NEXP] = {0,0,0,0,0,0,0,0};
            rowc[i0] = g0; rowc[i1] = g1;
            float4* cr = (float4*)(combine + (size_t)t * NEXP);
            cr[0] = make_float4(rowc[0], rowc[1], rowc[2], rowc[3]);
            cr[1] = make_float4(rowc[4], rowc[5], rowc[6], rowc[7]);
            #pragma unroll
            for (int e = 0; e < NEXP; ++e) atomicAdd(&s_ps[e], p[e]);
            int r0 = atomicAdd(&s_cnt[i0], 1);
            int r1 = atomicAdd(&s_cnt[i1], 1);
            s_ei[tl][0] = i0; s_rk[tl][0] = r0;
            s_ei[tl][1] = i1; s_rk[tl][1] = r1;
        }
    }
    __syncthreads();
    if (tid < NEXP) {
        s_base[tid] = atomicAdd(&counts[tid], s_cnt[tid]);
        atomicAdd(&prob_sums[tid], s_ps[tid]);
    }
    __syncthreads();
    if (tid < TPB_TOK * 2) {
        int tl = tid >> 1, k = tid & 1;
        int e = s_ei[tl][k];
        idxcap[e * T_TOK + s_base[e] + s_rk[tl][k]] = t0 + tl;
    }
}

// ---------------- plan: offsets, 64-row tile table, aux loss (1 thread) ----------------
__global__ void plan_kernel(const int* __restrict__ counts, const float* __restrict__ prob_sums,
                            int* __restrict__ offs, int* __restrict__ tile_e,
                            int* __restrict__ tile_s0, int* __restrict__ tile_nv,
                            int* __restrict__ ntiles, float* __restrict__ aux_out) {
    int tt = 0, o = 0;
    for (int e = 0; e < NEXP; ++e) {
        offs[e] = o;
        int n = counts[e];
        int nt = (n + 63) >> 6;
        for (int r = 0; r < nt; ++r) {
            tile_e[tt] = e;
            tile_s0[tt] = o + r * 64;
            int nv = n - r * 64; if (nv > 64) nv = 64;
            tile_nv[tt] = nv;
            ++tt;
        }
        o += nt * 64;
    }
    *ntiles = tt;
    float aux = 0.f;
    for (int e = 0; e < NEXP; ++e)
        aux += ((float)counts[e] / (float)(T_TOK * 2)) * (prob_sums[e] / (float)T_TOK);
    aux_out[0] = (float)NEXP * aux * 0.01f;
}

// ---------------- compact token list ----------------
__global__ void compact_kernel(const int* __restrict__ counts, const int* __restrict__ offs,
                               const int* __restrict__ tile_e, const int* __restrict__ tile_s0,
                               const int* __restrict__ ntiles,
                               const int* __restrict__ idxcap, int* __restrict__ idxc) {
    int tt = blockIdx.x;
    if (tt >= *ntiles) return;
    int e = tile_e[tt];
    int slot = tile_s0[tt] + threadIdx.x;
    int i = slot - offs[e];
    int n = counts[e];
    idxc[slot] = (i < n) ? idxcap[e * T_TOK + i] : 0;
}

// ============ GEMM template: BM=64 BN=128 BK=64, 128 threads (2 waves) ============
// LDS 24.8 KB -> ~6 blocks/CU co-resident (TLP latency cover). Same verified
// 0-conflict XOR swizzle as R6: LDS slot s of row r holds global k-slot s^(r&7);
// global source pre-swizzled, global_load_lds dest linear, ds_read swizzled.
// Per gload_lds inst (wave-uniform base): 64 lanes x 16B = 8 rows of 128B.

// ---------------- GEMM1: h[slot] = gelu(x[tok] @ w1[e] + b1[e]) ----------------
__global__ __launch_bounds__(128, 3)
void gemm1_kernel(const __hip_bfloat16* __restrict__ xb,    // [T][H]
                  const __hip_bfloat16* __restrict__ w1b,   // [E][INTER][H]  (K-major)
                  const float* __restrict__ b1,             // [E][INTER]
                  const int* __restrict__ idxc,
                  const int* __restrict__ tile_e, const int* __restrict__ tile_s0,
                  const int* __restrict__ ntiles,
                  __hip_bfloat16* __restrict__ h)           // [MSLOT64][INTER]
{
    const int NWG = MAXT64 * (INTER / 128);                 // 4352, %8==0
    int bid = blockIdx.x;
    int w = (bid & 7) * (NWG / 8) + (bid >> 3);             // XCD-chunked
    int tt = w >> 5;                                        // n0-fast
    int n0 = (w & 31) * 128;
    if (tt >= *ntiles) return;
    int e = tile_e[tt];
    int slot0 = tile_s0[tt];

    __shared__ __hip_bfloat16 As[64][64];
    __shared__ __hip_bfloat16 Bs[128][64];
    __shared__ int s_idx[64];

    int tid = threadIdx.x, wid = tid >> 6, ln = tid & 63;
    if (tid < 64) s_idx[tid] = idxc[slot0 + tid];
    __syncthreads();

    int sg = ((ln & 7) ^ ((ln >> 3) & 7)) * 8;              // pre-swizzled k-offset (elems)
    // A: wave wid round j covers rows j*16 + wid*8 .. +8 ; this lane's row:
    unsigned offA[4];
    #pragma unroll
    for (int j = 0; j < 4; ++j)
        offA[j] = (unsigned)(s_idx[j * 16 + wid * 8 + (ln >> 3)] * HID) + sg;
    // B: row j*16 + wid*8 + (ln>>3); consecutive j differ by 16*HID (const)
    unsigned offB0 = (unsigned)((e * INTER + n0 + wid * 8 + (ln >> 3)) * HID) + sg;

    f32x4 acc[4][4] = {};
    int lr = ln & 15;

    for (int kt = 0; kt < HID; kt += 64) {
        #pragma unroll
        for (int j = 0; j < 4; ++j)
            load_lds16(xb + offA[j] + kt, (void*)&As[j * 16 + wid * 8][0]);
        #pragma unroll
        for (int j = 0; j < 8; ++j)
            load_lds16(w1b + offB0 + j * 16 * HID + kt, (void*)&Bs[j * 16 + wid * 8][0]);
        __syncthreads();
        #pragma unroll
        for (int kk = 0; kk < 2; ++kk) {
            int lslot = (((kk * 4) + (ln >> 4)) ^ (ln & 7)) * 16;
            s16x8 af[4], bf[4];
            #pragma unroll
            for (int m = 0; m < 4; ++m) {
                int row = m * 16 + lr;
                af[m] = *(const s16x8*)((const char*)&As[0][0] + row * 128 + lslot);
            }
            #pragma unroll
            for (int n = 0; n < 4; ++n) {
                int row = wid * 64 + n * 16 + lr;
                bf[n] = *(const s16x8*)((const char*)&Bs[0][0] + row * 128 + lslot);
            }
            #pragma unroll
            for (int m = 0; m < 4; ++m)
                #pragma unroll
                for (int n = 0; n < 4; ++n)
                    acc[m][n] = __builtin_amdgcn_mfma_f32_16x16x32_bf16(af[m], bf[n], acc[m][n], 0, 0, 0);
        }
        __syncthreads();
    }

    const float* b1e = b1 + (size_t)e * INTER;
    int rq = (ln >> 4) * 4;
    #pragma unroll
    for (int m = 0; m < 4; ++m) {
        #pragma unroll
        for (int r = 0; r < 4; ++r) {
            int row = m * 16 + rq + r;
            size_t hrow = (size_t)(slot0 + row) * INTER;
            #pragma unroll
            for (int n = 0; n < 4; ++n) {
                int col = n0 + wid * 64 + n * 16 + lr;
                float v = acc[m][n][r] + b1e[col];
                h[hrow + col] = __float2bfloat16(gelu_tanh(v));
            }
        }
    }
}

// ---------------- GEMM2 (split-K=2): out[tok] += g * (h[slot] @ w2[e] + b2[e]) ----------------
__global__ __launch_bounds__(128, 3)
void gemm2_kernel(const __hip_bfloat16* __restrict__ h,     // [MSLOT64][INTER]
                  const __hip_bfloat16* __restrict__ w2b,   // [E][H][INTER]  (K-major)
                  const float* __restrict__ b2,             // [E][H]
                  const float* __restrict__ combine,        // [T][E]
                  const int* __restrict__ idxc,
                  const int* __restrict__ tile_e, const int* __restrict__ tile_s0,
                  const int* __restrict__ tile_nv, const int* __restrict__ ntiles,
                  float* __restrict__ out)                  // [T][H]
{
    const int NWG = MAXT64 * (HID / 128) * 2;               // 2176, %8==0
    int bid = blockIdx.x;
    int w = (bid & 7) * (NWG / 8) + (bid >> 3);             // XCD-chunked
    int ks = w & 1;                                         // split-K half
    int n0 = ((w >> 1) & 7) * 128;
    int tt = w >> 4;
    if (tt >= *ntiles) return;
    int e = tile_e[tt];
    int slot0 = tile_s0[tt];

    __shared__ __hip_bfloat16 As[64][64];
    __shared__ __hip_bfloat16 Bs[128][64];
    __shared__ int s_idx[64];

    int tid = threadIdx.x, wid = tid >> 6, ln = tid & 63;
    if (tid < 64) s_idx[tid] = idxc[slot0 + tid];
    __syncthreads();

    int sg = ((ln & 7) ^ ((ln >> 3) & 7)) * 8;
    // A rows are slot-contiguous: base + j*16*INTER
    unsigned offA0 = (unsigned)((slot0 + wid * 8 + (ln >> 3)) * INTER) + sg;
    unsigned offB0 = (unsigned)((e * HID + n0 + wid * 8 + (ln >> 3)) * INTER) + sg;

    f32x4 acc[4][4] = {};
    int lr = ln & 15;

    int k0 = ks * (INTER / 2), k1 = k0 + INTER / 2;         // 2048 K per block
    for (int kt = k0; kt < k1; kt += 64) {
        #pragma unroll
        for (int j = 0; j < 4; ++j)
            load_lds16(h + offA0 + j * 16 * INTER + kt, (void*)&As[j * 16 + wid * 8][0]);
        #pragma unroll
        for (int j = 0; j < 8; ++j)
            load_lds16(w2b + offB0 + j * 16 * INTER + kt, (void*)&Bs[j * 16 + wid * 8][0]);
        __syncthreads();
        #pragma unroll
        for (int kk = 0; kk < 2; ++kk) {
            int lslot = (((kk * 4) + (ln >> 4)) ^ (ln & 7)) * 16;
            s16x8 af[4], bf[4];
            #pragma unroll
            for (int m = 0; m < 4; ++m) {
                int row = m * 16 + lr;
                af[m] = *(const s16x8*)((const char*)&As[0][0] + row * 128 + lslot);
            }
            #pragma unroll
            for (int n = 0; n < 4; ++n) {
                int row = wid * 64 + n * 16 + lr;
                bf[n] = *(const s16x8*)((const char*)&Bs[0][0] + row * 128 + lslot);
            }
            #pragma unroll
            for (int m = 0; m < 4; ++m)
                #pragma unroll
                for (int n = 0; n < 4; ++n)
                    acc[m][n] = __builtin_amdgcn_mfma_f32_16x16x32_bf16(af[m], bf[n], acc[m][n], 0, 0, 0);
        }
        __syncthreads();
    }

    const float* b2e = b2 + (size_t)e * HID;
    int nv = tile_nv[tt];
    int rq = (ln >> 4) * 4;
    #pragma unroll
    for (int m = 0; m < 4; ++m) {
        #pragma unroll
        for (int r = 0; r < 4; ++r) {
            int row = m * 16 + rq + r;
            if (row < nv) {
                int tok = s_idx[row];
                float g = combine[(size_t)tok * 8 + e];
                #pragma unroll
                for (int n = 0; n < 4; ++n) {
                    int col = n0 + wid * 64 + n * 16 + lr;
                    float v = acc[m][n][r] + (ks == 0 ? b2e[col] : 0.f);
                    atomicAdd(&out[(size_t)tok * HID + col], g * v);
                }
            }
        }
    }
}

// ---------------- workspace layout ----------------
static const size_t OFF_XB      = 0;
static const size_t SZ_XB       = (size_t)T_TOK * HID * 2;
static const size_t OFF_W1B     = OFF_XB + SZ_XB;
static const size_t SZ_W        = (size_t)NEXP * INTER * HID * 2;
static const size_t OFF_W2B     = OFF_W1B + SZ_W;
static const size_t OFF_H       = OFF_W2B + SZ_W;
static const size_t SZ_H        = (size_t)MSLOT64 * INTER * 2;
static const size_t OFF_COMBINE = OFF_H + SZ_H;
static const size_t OFF_IDXCAP  = OFF_COMBINE + (size_t)T_TOK * 8 * 4;
static const size_t OFF_IDXC    = OFF_IDXCAP + (size_t)NEXP * T_TOK * 4;
static const size_t OFF_COUNTS  = OFF_IDXC + (size_t)MSLOT64 * 4;   // 8 ints
static const size_t OFF_PSUMS   = OFF_COUNTS + 32;                  // 8 floats
static const size_t OFF_OFFS    = OFF_PSUMS + 32;                   // 8 ints
static const size_t OFF_TILE_E  = OFF_OFFS + 64;
static const size_t OFF_TILE_S0 = OFF_TILE_E + 1024;                // 136 ints each
static const size_t OFF_TILE_NV = OFF_TILE_S0 + 1024;
static const size_t OFF_NTILES  = OFF_TILE_NV + 1024;

extern "C" void kernel_launch(void* const* d_in, const int* in_sizes, int n_in,
                              void* d_out, int out_size, void* d_ws, size_t ws_size,
                              hipStream_t stream) {
    const float* x  = (const float*)d_in[0];
    const float* Wg = (const float*)d_in[1];
    const float* w1 = (const float*)d_in[2];
    const float* b1 = (const float*)d_in[3];
    const float* w2 = (const float*)d_in[4];
    const float* b2 = (const float*)d_in[5];
    float* out = (float*)d_out;
    char* ws = (char*)d_ws;

    __hip_bfloat16* xb   = (__hip_bfloat16*)(ws + OFF_XB);
    __hip_bfloat16* w1b  = (__hip_bfloat16*)(ws + OFF_W1B);
    __hip_bfloat16* w2b  = (__hip_bfloat16*)(ws + OFF_W2B);
    __hip_bfloat16* h    = (__hip_bfloat16*)(ws + OFF_H);
    float* combine       = (float*)(ws + OFF_COMBINE);
    int*   idxcap        = (int*)(ws + OFF_IDXCAP);
    int*   idxc          = (int*)(ws + OFF_IDXC);
    int*   counts        = (int*)(ws + OFF_COUNTS);
    float* psums         = (float*)(ws + OFF_PSUMS);
    int*   offs          = (int*)(ws + OFF_OFFS);
    int*   tile_e        = (int*)(ws + OFF_TILE_E);
    int*   tile_s0       = (int*)(ws + OFF_TILE_S0);
    int*   tile_nv       = (int*)(ws + OFF_TILE_NV);
    int*   ntiles        = (int*)(ws + OFF_NTILES);

    (void)hipMemsetAsync(out, 0, (size_t)out_size * sizeof(float), stream);
    (void)hipMemsetAsync(ws + OFF_COUNTS, 0, 64, stream);

    transpose_bf16_kernel<<<dim3(INTER / 64, HID / 64, NEXP), 256, 0, stream>>>(w1, w1b, HID, INTER);
    transpose_bf16_kernel<<<dim3(HID / 64, INTER / 64, NEXP), 256, 0, stream>>>(w2, w2b, INTER, HID);
    gating_kernel<<<T_TOK / TPB_TOK, 256, 0, stream>>>(x, Wg, xb, combine, counts, psums, idxcap);
    plan_kernel<<<1, 1, 0, stream>>>(counts, psums, offs, tile_e, tile_s0, tile_nv, ntiles,
                                     out + (size_t)T_TOK * HID);
    compact_kernel<<<MAXT64, 64, 0, stream>>>(counts, offs, tile_e, tile_s0, ntiles, idxcap, idxc);
    gemm1_kernel<<<MAXT64 * (INTER / 128), 128, 0, stream>>>(xb, w1b, b1, idxc, tile_e, tile_s0,
                                                             ntiles, h);
    gemm2_kernel<<<MAXT64 * (HID / 128) * 2, 128, 0, stream>>>(h, w2b, b2, combine, idxc, tile_e,
                                                               tile_s0, tile_nv, ntiles, out);
}

// Round 13
// 381.055 us; speedup vs baseline: 1.3617x; 1.0187x over previous
//
#include <hip/hip_runtime.h>
#include <hip/hip_bf16.h>

// ---------------- constants ----------------
#define T_TOK   4096
#define HID     1024
#define INTER   4096
#define NEXP    8
#define MAXT    72          // max total row-tiles: (8192 + 8*127)/128 = 72
#define MAXSLOT 9216        // MAXT * 128
#define TPB_TOK 16          // tokens per gating block

typedef __attribute__((ext_vector_type(8))) short s16x8;
typedef __attribute__((ext_vector_type(4))) float f32x4;

__device__ __forceinline__ void load_lds16(const void* g, void* l) {
    __builtin_amdgcn_global_load_lds(
        (const __attribute__((address_space(1))) void*)g,
        (__attribute__((address_space(3))) void*)l, 16, 0, 0);
}

// gelu(tanh approx) = v * sigmoid(2*z), z = c*(v + 0.044715 v^3)
__device__ __forceinline__ float gelu_tanh(float v) {
    float c = 0.7978845608028654f;
    float z = c * (v + 0.044715f * v * v * v);
    return v / (1.0f + __expf(-2.0f * z));
}

// ---------------- transpose+convert weights: in [E][R][C] f32 -> out [E][C][R] bf16 ----------------
__global__ void transpose_bf16_kernel(const float* __restrict__ in, __hip_bfloat16* __restrict__ out,
                                      int R, int C) {
    __shared__ float tile[64][65];
    size_t eoff = (size_t)blockIdx.z * R * C;
    int c0 = blockIdx.x * 64, r0 = blockIdx.y * 64;
    int tid = threadIdx.x;

    int lr = tid >> 4;            // 0..15
    int lc = (tid & 15) * 4;
    #pragma unroll
    for (int it = 0; it < 4; ++it) {
        int r = it * 16 + lr;
        float4 v = *(const float4*)(in + eoff + (size_t)(r0 + r) * C + c0 + lc);
        tile[r][lc + 0] = v.x; tile[r][lc + 1] = v.y;
        tile[r][lc + 2] = v.z; tile[r][lc + 3] = v.w;
    }
    __syncthreads();

    int oc = tid >> 3;            // 0..31
    int r8 = (tid & 7) * 8;
    #pragma unroll
    for (int it = 0; it < 2; ++it) {
        int c = it * 32 + oc;
        alignas(16) __hip_bfloat16 o[8];
        #pragma unroll
        for (int j = 0; j < 8; ++j) o[j] = __float2bfloat16(tile[r8 + j][c]);
        *(s16x8*)(out + eoff + (size_t)(c0 + c) * R + r0 + r8) = *(const s16x8*)o;
    }
}

// ---------------- gating: 16 tokens per block, block-aggregated atomics ----------------
__global__ void gating_kernel(const float* __restrict__ x, const float* __restrict__ Wg,
                              __hip_bfloat16* __restrict__ xb,
                              float* __restrict__ combine, int* __restrict__ counts,
                              float* __restrict__ prob_sums, int* __restrict__ idxcap) {
    __shared__ float s_ps[NEXP];
    __shared__ int   s_cnt[NEXP];
    __shared__ int   s_base[NEXP];
    __shared__ int   s_ei[TPB_TOK][2];
    __shared__ int   s_rk[TPB_TOK][2];

    int tid = threadIdx.x, wv = tid >> 6, ln = tid & 63;
    if (tid < NEXP) { s_ps[tid] = 0.f; s_cnt[tid] = 0; }
    __syncthreads();

    int t0 = blockIdx.x * TPB_TOK;
    for (int sub = 0; sub < 4; ++sub) {
        int tl = wv * 4 + sub;          // 0..15 local token
        int t = t0 + tl;
        const float* xr = x + (size_t)t * HID + ln * 16;
        float4 xv[4];
        #pragma unroll
        for (int i = 0; i < 4; ++i) xv[i] = *(const float4*)(xr + i * 4);

        alignas(16) __hip_bfloat16 row[16];
        #pragma unroll
        for (int i = 0; i < 4; ++i) {
            row[i * 4 + 0] = __float2bfloat16(xv[i].x);
            row[i * 4 + 1] = __float2bfloat16(xv[i].y);
            row[i * 4 + 2] = __float2bfloat16(xv[i].z);
            row[i * 4 + 3] = __float2bfloat16(xv[i].w);
        }
        __hip_bfloat16* xbr = xb + (size_t)t * HID + ln * 16;
        *(s16x8*)(xbr)     = *(s16x8*)&row[0];
        *(s16x8*)(xbr + 8) = *(s16x8*)&row[8];

        float acc[NEXP] = {0,0,0,0,0,0,0,0};
        #pragma unroll
        for (int i = 0; i < 4; ++i) {
            float xs[4] = {xv[i].x, xv[i].y, xv[i].z, xv[i].w};
            #pragma unroll
            for (int j = 0; j < 4; ++j) {
                int k = ln * 16 + i * 4 + j;
                float4 wa = *(const float4*)(Wg + (size_t)k * 8);
                float4 wb = *(const float4*)(Wg + (size_t)k * 8 + 4);
                acc[0] += xs[j] * wa.x; acc[1] += xs[j] * wa.y;
                acc[2] += xs[j] * wa.z; acc[3] += xs[j] * wa.w;
                acc[4] += xs[j] * wb.x; acc[5] += xs[j] * wb.y;
                acc[6] += xs[j] * wb.z; acc[7] += xs[j] * wb.w;
            }
        }
        #pragma unroll
        for (int e = 0; e < NEXP; ++e)
            #pragma unroll
            for (int off = 32; off >= 1; off >>= 1)
                acc[e] += __shfl_xor(acc[e], off);

        float m = acc[0];
        #pragma unroll
        for (int e = 1; e < NEXP; ++e) m = fmaxf(m, acc[e]);
        float p[NEXP], s = 0.f;
        #pragma unroll
        for (int e = 0; e < NEXP; ++e) { p[e] = __expf(acc[e] - m); s += p[e]; }
        float inv = 1.0f / s;
        #pragma unroll
        for (int e = 0; e < NEXP; ++e) p[e] *= inv;

        int i0 = 0;
        #pragma unroll
        for (int e = 1; e < NEXP; ++e) if (p[e] > p[i0]) i0 = e;
        int i1 = (i0 == 0) ? 1 : 0;
        #pragma unroll
        for (int e = 0; e < NEXP; ++e) if (e != i0 && p[e] > p[i1]) i1 = e;
        float gs = p[i0] + p[i1];
        float g0 = p[i0] / gs, g1 = p[i1] / gs;

        if (ln == 0) {
            float rowc[NEXP] = {0,0,0,0,0,0,0,0};
            rowc[i0] = g0; rowc[i1] = g1;
            float4* cr = (float4*)(combine + (size_t)t * NEXP);
            cr[0] = make_float4(rowc[0], rowc[1], rowc[2], rowc[3]);
            cr[1] = make_float4(rowc[4], rowc[5], rowc[6], rowc[7]);
            #pragma unroll
            for (int e = 0; e < NEXP; ++e) atomicAdd(&s_ps[e], p[e]);
            int r0 = atomicAdd(&s_cnt[i0], 1);
            int r1 = atomicAdd(&s_cnt[i1], 1);
            s_ei[tl][0] = i0; s_rk[tl][0] = r0;
            s_ei[tl][1] = i1; s_rk[tl][1] = r1;
        }
    }
    __syncthreads();
    if (tid < NEXP) {
        s_base[tid] = atomicAdd(&counts[tid], s_cnt[tid]);
        atomicAdd(&prob_sums[tid], s_ps[tid]);
    }
    __syncthreads();
    if (tid < TPB_TOK * 2) {
        int tl = tid >> 1, k = tid & 1;
        int e = s_ei[tl][k];
        idxcap[e * T_TOK + s_base[e] + s_rk[tl][k]] = t0 + tl;
    }
}

// ---------------- plan: offsets, tile table, aux loss (1 thread) ----------------
__global__ void plan_kernel(const int* __restrict__ counts, const float* __restrict__ prob_sums,
                            int* __restrict__ offs, int* __restrict__ tile_e,
                            int* __restrict__ tile_s0, int* __restrict__ tile_nv,
                            int* __restrict__ ntiles, float* __restrict__ aux_out) {
    int tt = 0, o = 0;
    for (int e = 0; e < NEXP; ++e) {
        offs[e] = o;
        int n = counts[e];
        int nt = (n + 127) >> 7;
        for (int r = 0; r < nt; ++r) {
            tile_e[tt] = e;
            tile_s0[tt] = o + r * 128;
            int nv = n - r * 128; if (nv > 128) nv = 128;
            tile_nv[tt] = nv;
            ++tt;
        }
        o += nt * 128;
    }
    *ntiles = tt;
    float aux = 0.f;
    for (int e = 0; e < NEXP; ++e)
        aux += ((float)counts[e] / (float)(T_TOK * 2)) * (prob_sums[e] / (float)T_TOK);
    aux_out[0] = (float)NEXP * aux * 0.01f;
}

// ---------------- compact token list ----------------
__global__ void compact_kernel(const int* __restrict__ counts, const int* __restrict__ offs,
                               const int* __restrict__ tile_e, const int* __restrict__ tile_s0,
                               const int* __restrict__ ntiles,
                               const int* __restrict__ idxcap, int* __restrict__ idxc) {
    int tt = blockIdx.x;
    if (tt >= *ntiles) return;
    int e = tile_e[tt];
    int slot = tile_s0[tt] + threadIdx.x;
    int i = slot - offs[e];
    int n = counts[e];
    idxc[slot] = (i < n) ? idxcap[e * T_TOK + i] : 0;
}

// ============ GEMM templates (R6 base) ============
// Single-buffered BK=64, two barriers/iter. Verified 0-conflict XOR swizzle:
// LDS slot s of row r holds global k-slot s^(r&7); source pre-swizzled,
// global_load_lds dest linear, ds_read swizzled.

// ---------------- GEMM1: BM=128 BN=256 BK=64, 4 waves (2x2 of 64x128) ----------------
__global__ __launch_bounds__(256, 2)
void gemm1_kernel(const __hip_bfloat16* __restrict__ xb,    // [T][H]
                  const __hip_bfloat16* __restrict__ w1b,   // [E][INTER][H]  (K-major)
                  const float* __restrict__ b1,             // [E][INTER]
                  const int* __restrict__ idxc,
                  const int* __restrict__ tile_e, const int* __restrict__ tile_s0,
                  const int* __restrict__ ntiles,
                  __hip_bfloat16* __restrict__ h)           // [MAXSLOT][INTER]
{
    const int NWG = MAXT * (INTER / 256);                   // 1152, %8==0
    int bid = blockIdx.x;
    int w = (bid & 7) * (NWG / 8) + (bid >> 3);             // XCD-chunked
    int tt = w >> 4;                                        // n0-fast
    int n0 = (w & 15) * 256;
    if (tt >= *ntiles) return;
    int e = tile_e[tt];
    int slot0 = tile_s0[tt];

    __shared__ __hip_bfloat16 As[128][64];
    __shared__ __hip_bfloat16 Bs[256][64];
    __shared__ int s_idx[128];

    int tid = threadIdx.x, wv = tid >> 6, ln = tid & 63;
    if (tid < 128) s_idx[tid] = idxc[slot0 + tid];
    __syncthreads();

    int swz = ((ln & 7) ^ (ln >> 3)) * 8;                   // pre-swizzled k-offset (elems)
    unsigned offA[4];
    #pragma unroll
    for (int j = 0; j < 4; ++j)
        offA[j] = (unsigned)(s_idx[wv * 32 + j * 8 + (ln >> 3)] * HID) + swz;
    unsigned offB0 = (unsigned)((e * INTER + n0 + wv * 64 + (ln >> 3)) * HID) + swz;

    f32x4 acc[4][8] = {};
    int wr = wv >> 1, wc = wv & 1, lr = ln & 15;

    for (int kt = 0; kt < HID; kt += 64) {
        #pragma unroll
        for (int j = 0; j < 4; ++j)
            load_lds16(xb + offA[j] + kt, (void*)&As[wv * 32 + j * 8][0]);
        #pragma unroll
        for (int j = 0; j < 8; ++j)
            load_lds16(w1b + offB0 + j * 8 * HID + kt, (void*)&Bs[wv * 64 + j * 8][0]);
        __syncthreads();
        #pragma unroll
        for (int kk = 0; kk < 2; ++kk) {
            int lslot = (((kk * 4) + (ln >> 4)) ^ (ln & 7)) * 16;
            s16x8 af[4], bf[8];
            #pragma unroll
            for (int m = 0; m < 4; ++m) {
                int row = wr * 64 + m * 16 + lr;
                af[m] = *(const s16x8*)((const char*)&As[0][0] + row * 128 + lslot);
            }
            #pragma unroll
            for (int n = 0; n < 8; ++n) {
                int row = wc * 128 + n * 16 + lr;
                bf[n] = *(const s16x8*)((const char*)&Bs[0][0] + row * 128 + lslot);
            }
            #pragma unroll
            for (int m = 0; m < 4; ++m)
                #pragma unroll
                for (int n = 0; n < 8; ++n)
                    acc[m][n] = __builtin_amdgcn_mfma_f32_16x16x32_bf16(af[m], bf[n], acc[m][n], 0, 0, 0);
        }
        __syncthreads();
    }

    const float* b1e = b1 + (size_t)e * INTER;
    int rq = (ln >> 4) * 4;
    #pragma unroll
    for (int m = 0; m < 4; ++m) {
        #pragma unroll
        for (int r = 0; r < 4; ++r) {
            int row = wr * 64 + m * 16 + rq + r;
            size_t hrow = (size_t)(slot0 + row) * INTER;
            #pragma unroll
            for (int n = 0; n < 8; ++n) {
                int col = n0 + wc * 128 + n * 16 + lr;
                float v = acc[m][n][r] + b1e[col];
                h[hrow + col] = __float2bfloat16(gelu_tanh(v));
            }
        }
    }
}

// ---------------- GEMM2 (split-K=2): out[tok] += g * (h[slot] @ w2[e] + b2[e]) ----------------
__global__ __launch_bounds__(256, 3)
void gemm2_kernel(const __hip_bfloat16* __restrict__ h,     // [MAXSLOT][INTER]
                  const __hip_bfloat16* __restrict__ w2b,   // [E][H][INTER]  (K-major)
                  const float* __restrict__ b2,             // [E][H]
                  const float* __restrict__ combine,        // [T][E]
                  const int* __restrict__ idxc,
                  const int* __restrict__ tile_e, const int* __restrict__ tile_s0,
                  const int* __restrict__ tile_nv, const int* __restrict__ ntiles,
                  float* __restrict__ out)                  // [T][H]
{
    const int NWG = MAXT * (HID / 128) * 2;                 // 1152, %8==0
    int bid = blockIdx.x;
    int w = (bid & 7) * (NWG / 8) + (bid >> 3);             // XCD-chunked
    int ks = w & 1;                                         // split-K half
    int n0 = ((w >> 1) & 7) * 128;
    int tt = w >> 4;
    if (tt >= *ntiles) return;
    int e = tile_e[tt];
    int slot0 = tile_s0[tt];

    __shared__ __hip_bfloat16 As[128][64];
    __shared__ __hip_bfloat16 Bs[128][64];
    __shared__ int s_idx[128];

    int tid = threadIdx.x, wv = tid >> 6, ln = tid & 63;
    if (tid < 128) s_idx[tid] = idxc[slot0 + tid];
    __syncthreads();

    int swz = ((ln & 7) ^ (ln >> 3)) * 8;
    const __hip_bfloat16* srcA[4];
    const __hip_bfloat16* srcB[4];
    const __hip_bfloat16* wbase = w2b + (size_t)e * HID * INTER;
    #pragma unroll
    for (int j = 0; j < 4; ++j) {
        int r = wv * 32 + j * 8 + (ln >> 3);
        srcA[j] = h + (size_t)(slot0 + r) * INTER + swz;
        srcB[j] = wbase + (size_t)(n0 + r) * INTER + swz;
    }

    f32x4 acc[4][4] = {};
    int wr = wv >> 1, wc = wv & 1, lr = ln & 15;

    int k0 = ks * (INTER / 2), k1 = k0 + INTER / 2;
    for (int kt = k0; kt < k1; kt += 64) {
        #pragma unroll
        for (int j = 0; j < 4; ++j) {
            load_lds16(srcA[j] + kt, (void*)&As[wv * 32 + j * 8][0]);
            load_lds16(srcB[j] + kt, (void*)&Bs[wv * 32 + j * 8][0]);
        }
        __syncthreads();
        #pragma unroll
        for (int kk = 0; kk < 2; ++kk) {
            int lslot = (((kk * 4) + (ln >> 4)) ^ (ln & 7)) * 16;
            s16x8 af[4], bf[4];
            #pragma unroll
            for (int m = 0; m < 4; ++m) {
                int row = wr * 64 + m * 16 + lr;
                af[m] = *(const s16x8*)((const char*)&As[0][0] + row * 128 + lslot);
            }
            #pragma unroll
            for (int n = 0; n < 4; ++n) {
                int row = wc * 64 + n * 16 + lr;
                bf[n] = *(const s16x8*)((const char*)&Bs[0][0] + row * 128 + lslot);
            }
            #pragma unroll
            for (int m = 0; m < 4; ++m)
                #pragma unroll
                for (int n = 0; n < 4; ++n)
                    acc[m][n] = __builtin_amdgcn_mfma_f32_16x16x32_bf16(af[m], bf[n], acc[m][n], 0, 0, 0);
        }
        __syncthreads();
    }

    const float* b2e = b2 + (size_t)e * HID;
    int nv = tile_nv[tt];
    int rq = (ln >> 4) * 4;
    #pragma unroll
    for (int m = 0; m < 4; ++m) {
        #pragma unroll
        for (int r = 0; r < 4; ++r) {
            int row = wr * 64 + m * 16 + rq + r;
            if (row < nv) {
                int tok = s_idx[row];
                float g = combine[(size_t)tok * 8 + e];
                #pragma unroll
                for (int n = 0; n < 4; ++n) {
                    int col = n0 + wc * 64 + n * 16 + lr;
                    float v = acc[m][n][r] + (ks == 0 ? b2e[col] : 0.f);
                    atomicAdd(&out[(size_t)tok * HID + col], g * v);
                }
            }
        }
    }
}

// ---------------- workspace layout ----------------
static const size_t OFF_XB      = 0;
static const size_t SZ_XB       = (size_t)T_TOK * HID * 2;
static const size_t OFF_W1B     = OFF_XB + SZ_XB;
static const size_t SZ_W        = (size_t)NEXP * INTER * HID * 2;
static const size_t OFF_W2B     = OFF_W1B + SZ_W;
static const size_t OFF_H       = OFF_W2B + SZ_W;
static const size_t SZ_H        = (size_t)MAXSLOT * INTER * 2;
static const size_t OFF_COMBINE = OFF_H + SZ_H;
static const size_t OFF_IDXCAP  = OFF_COMBINE + (size_t)T_TOK * 8 * 4;
static const size_t OFF_IDXC    = OFF_IDXCAP + (size_t)NEXP * T_TOK * 4;
static const size_t OFF_COUNTS  = OFF_IDXC + (size_t)MAXSLOT * 4;   // 8 ints
static const size_t OFF_PSUMS   = OFF_COUNTS + 32;                  // 8 floats
static const size_t OFF_OFFS    = OFF_PSUMS + 32;                   // 8 ints
static const size_t OFF_TILE_E  = OFF_OFFS + 64;
static const size_t OFF_TILE_S0 = OFF_TILE_E + 512;
static const size_t OFF_TILE_NV = OFF_TILE_S0 + 512;
static const size_t OFF_NTILES  = OFF_TILE_NV + 512;

extern "C" void kernel_launch(void* const* d_in, const int* in_sizes, int n_in,
                              void* d_out, int out_size, void* d_ws, size_t ws_size,
                              hipStream_t stream) {
    const float* x  = (const float*)d_in[0];
    const float* Wg = (const float*)d_in[1];
    const float* w1 = (const float*)d_in[2];
    const float* b1 = (const float*)d_in[3];
    const float* w2 = (const float*)d_in[4];
    const float* b2 = (const float*)d_in[5];
    float* out = (float*)d_out;
    char* ws = (char*)d_ws;

    __hip_bfloat16* xb   = (__hip_bfloat16*)(ws + OFF_XB);
    __hip_bfloat16* w1b  = (__hip_bfloat16*)(ws + OFF_W1B);
    __hip_bfloat16* w2b  = (__hip_bfloat16*)(ws + OFF_W2B);
    __hip_bfloat16* h    = (__hip_bfloat16*)(ws + OFF_H);
    float* combine       = (float*)(ws + OFF_COMBINE);
    int*   idxcap        = (int*)(ws + OFF_IDXCAP);
    int*   idxc          = (int*)(ws + OFF_IDXC);
    int*   counts        = (int*)(ws + OFF_COUNTS);
    float* psums         = (float*)(ws + OFF_PSUMS);
    int*   offs          = (int*)(ws + OFF_OFFS);
    int*   tile_e        = (int*)(ws + OFF_TILE_E);
    int*   tile_s0       = (int*)(ws + OFF_TILE_S0);
    int*   tile_nv       = (int*)(ws + OFF_TILE_NV);
    int*   ntiles        = (int*)(ws + OFF_NTILES);

    (void)hipMemsetAsync(out, 0, (size_t)out_size * sizeof(float), stream);
    (void)hipMemsetAsync(ws + OFF_COUNTS, 0, 64, stream);

    transpose_bf16_kernel<<<dim3(INTER / 64, HID / 64, NEXP), 256, 0, stream>>>(w1, w1b, HID, INTER);
    transpose_bf16_kernel<<<dim3(HID / 64, INTER / 64, NEXP), 256, 0, stream>>>(w2, w2b, INTER, HID);
    gating_kernel<<<T_TOK / TPB_TOK, 256, 0, stream>>>(x, Wg, xb, combine, counts, psums, idxcap);
    plan_kernel<<<1, 1, 0, stream>>>(counts, psums, offs, tile_e, tile_s0, tile_nv, ntiles,
                                     out + (size_t)T_TOK * HID);
    compact_kernel<<<MAXT, 128, 0, stream>>>(counts, offs, tile_e, tile_s0, ntiles, idxcap, idxc);
    gemm1_kernel<<<MAXT * (INTER / 256), 256, 0, stream>>>(xb, w1b, b1, idxc, tile_e, tile_s0,
                                                           ntiles, h);
    gemm2_kernel<<<MAXT * (HID / 128) * 2, 256, 0, stream>>>(h, w2b, b2, combine, idxc, tile_e,
                                                             tile_s0, tile_nv, ntiles, out);
}